// Round 12
// baseline (323.949 us; speedup 1.0000x reference)
//
#include <hip/hip_runtime.h>

typedef __attribute__((ext_vector_type(8))) short short8;
typedef __attribute__((ext_vector_type(4))) float f32x4;

__device__ __forceinline__ float b2f(unsigned short u) {
  union { unsigned u32; float f; } x; x.u32 = ((unsigned)u) << 16; return x.f;
}
__device__ __forceinline__ unsigned short f2bf(float f) {
  union { float f; unsigned u; } x; x.f = f;
  unsigned r = x.u + 0x7fffu + ((x.u >> 16) & 1u);
  return (unsigned short)(r >> 16);
}
__device__ __forceinline__ void async_load16(const void* g, void* l) {
  __builtin_amdgcn_global_load_lds(
      (__attribute__((address_space(1))) void*)(void*)(g),
      (__attribute__((address_space(3))) void*)(l), 16, 0, 0);
}

// ---- merged: GroupNorm (blocks 0..1023) + weight fp32->bf16 cvt (blocks 1024..2047) ----
__global__ __launch_bounds__(256) void prep_k(
    const float* __restrict__ x, const float* __restrict__ gamma,
    const float* __restrict__ beta, unsigned short* __restrict__ hin,
    const float* __restrict__ wa, unsigned short* __restrict__ oa,
    const float* __restrict__ wb, unsigned short* __restrict__ ob) {
  if (blockIdx.x >= 1024) {
    int i = (blockIdx.x - 1024) * 256 + threadIdx.x;
    const float* src; unsigned short* dst; int idx;
    if (i < 196608) { src = wa; dst = oa; idx = i; }
    else if (i < 262144) { src = wb; dst = ob; idx = i - 196608; }
    else return;
    float4 v = ((const float4*)src)[idx];
    unsigned short o[4] __attribute__((aligned(8)));
    o[0] = f2bf(v.x); o[1] = f2bf(v.y); o[2] = f2bf(v.z); o[3] = f2bf(v.w);
    ((int2*)dst)[idx] = *(int2*)o;
    return;
  }
  const int b = blockIdx.x >> 5, g = blockIdx.x & 31;
  const float* xb = x + ((unsigned long long)b * 512ull + (unsigned long long)g * 16ull) * 1024ull;
  const int t = threadIdx.x;
  float4 xr[16];
  float s = 0.f, ss = 0.f;
#pragma unroll
  for (int c = 0; c < 16; ++c) {
    xr[c] = *(const float4*)(xb + c * 1024 + t * 4);
    s += xr[c].x + xr[c].y + xr[c].z + xr[c].w;
    ss += xr[c].x * xr[c].x + xr[c].y * xr[c].y + xr[c].z * xr[c].z + xr[c].w * xr[c].w;
  }
#pragma unroll
  for (int o = 32; o; o >>= 1) { s += __shfl_down(s, o); ss += __shfl_down(ss, o); }
  __shared__ float sred[8];
  if ((t & 63) == 0) { sred[t >> 6] = s; sred[4 + (t >> 6)] = ss; }
  __syncthreads();
  s = sred[0] + sred[1] + sred[2] + sred[3];
  ss = sred[4] + sred[5] + sred[6] + sred[7];
  const float mean = s * (1.f / 16384.f);
  const float rstd = rsqrtf(ss * (1.f / 16384.f) - mean * mean + 1e-5f);
  float ga[16], be[16];
#pragma unroll
  for (int c = 0; c < 16; ++c) {
    float gg = gamma[g * 16 + c] * rstd;
    ga[c] = gg;
    be[c] = beta[g * 16 + c] - mean * gg;
  }
#pragma unroll
  for (int p4 = 0; p4 < 4; ++p4) {
    unsigned short ov[16] __attribute__((aligned(16)));
#pragma unroll
    for (int c = 0; c < 16; ++c)
      ov[c] = f2bf(((const float*)&xr[c])[p4] * ga[c] + be[c]);
    unsigned short* dst = hin + ((unsigned long long)b * 1024ull + t * 4 + p4) * 512ull + g * 16;
    *(int4*)dst = *(int4*)ov;
    *(int4*)(dst + 8) = *(int4*)(ov + 8);
  }
}

// ---- GEMM: C[m][n] = sum_k A[m][k]*B[n][k], A/B bf16 K-contiguous, BK=64 ----
// 128x128 tile (MI=4), 256 threads / 4 waves (2Mx2N, per-wave 64x64).
// ROUND 12: double-buffered LDS (2 x 32 KB) + depth-2 counted-vmcnt pipeline —
// the m218 lever (counted vmcnt = +38-73% isolated) tested for the FIRST time
// at the 128-tile/multi-block geometry (rounds 1-4 only tried it at 256-tile /
// 1 block/CU where no independent waves existed). No setprio / no sched_barrier
// (both measured harmful here).
//   prologue: STAGE(t0,buf0) STAGE(t1,buf1)       [16 loads/thread in flight]
//   iter t:   vmcnt(8)  -> tile t landed, tile t+1 stays in flight ACROSS barrier
//             s_barrier -> all waves' tile-t loads landed (per-wave vmcnt + barrier)
//             COMPUTE buf[t&1]  (ds_read -> MFMA, compiler-managed lgkmcnt)
//             s_barrier -> all reads of buf[t&1] consumed (MFMAs precede barrier)
//             STAGE(t+2 -> buf[t&1])              [loads get a full iter to land]
//   last tile peeled with vmcnt(0).
// Cost: 64 KB LDS -> 2 blocks/CU (vs 2.6 single-buf). Gain: no per-K-step drain.
// Staging rows are 128 B; XOR swizzle chunk^(row&7) applied on the GLOBAL source
// (LDS dest linear per global_load_lds rules); readers un-XOR. Measured 0 conflicts.
// MODE 0: QKV (bias, scale q/k, V transposed [c][p]). XCD swizzle.
// MODE 1: S^T (A=K, B=Q) + segmented (32-j) softmax + 2-pass LDS transpose -> P[i][j].
// MODE 2: PV -> H[b][i][c] bf16.
// MODE 3: proj -> fout = x + bias + acc (fp32), LDS-staged coalesced epilogue.
template <int MODE, int MI>
__global__ __launch_bounds__(256, 2) void gemm_k(
    const unsigned short* __restrict__ A, unsigned long long sA, int lda,
    const unsigned short* __restrict__ B, unsigned long long sB, int ldb,
    const float* __restrict__ bias, const float* __restrict__ xres,
    unsigned short* __restrict__ out0, unsigned short* __restrict__ out1,
    unsigned short* __restrict__ out2, float* __restrict__ fout,
    float scale, int K) {
  constexpr int MBLK = MI * 32;  // 128
  constexpr int BUF_SHORTS = MBLK * 64 + 128 * 64;  // 16384 shorts = 32 KB per buffer
  __shared__ unsigned short smem[2 * BUF_SHORTS];   // 64 KB total
  const int tid = threadIdx.x;
  const int wave = tid >> 6, lane = tid & 63;

  int n_t, m_t, b;
  if (MODE == 0) {
    // 3072 blocks; 12 n-tiles of one (m,b) run consecutively per XCD -> A-tile L2 reuse
    const int L = blockIdx.x + gridDim.x * (blockIdx.y + gridDim.y * blockIdx.z);
    const int r8 = L & 7, q = L >> 3;
    n_t = q % 12;
    const int mb = (q / 12) * 8 + r8;
    m_t = mb & 7;
    b = mb >> 3;
  } else if (MODE == 1) {
    const int L = blockIdx.x + gridDim.x * (blockIdx.y + gridDim.y * blockIdx.z);
    const int slice = L & 7, t = L >> 3;
    b = slice * 4 + (t >> 6);
    const int rem = t & 63;
    m_t = rem >> 3;
    n_t = rem & 7;
  } else if (MODE == 2) {
    const int L = blockIdx.x + gridDim.x * (blockIdx.y + gridDim.y * blockIdx.z);
    const int slice = L & 7, t = L >> 3;
    b = slice * 4 + (t >> 5);
    const int rem = t & 31;
    m_t = rem >> 2;
    n_t = rem & 3;
  } else {
    n_t = blockIdx.x; m_t = blockIdx.y; b = blockIdx.z;
  }
  const int m0 = m_t * MBLK, n0 = n_t * 128;
  const int wm = (wave & 1) * (MI * 16), wn = (wave >> 1) * 64;
  const unsigned short* Ab = A + (unsigned long long)b * sA + (unsigned long long)m0 * lda;
  const unsigned short* Bb = B + (unsigned long long)b * sB + (unsigned long long)n0 * ldb;

  f32x4 acc[MI][4];
#pragma unroll
  for (int i = 0; i < MI; ++i)
#pragma unroll
    for (int j = 0; j < 4; ++j)
#pragma unroll
      for (int r = 0; r < 4; ++r) acc[i][j][r] = 0.f;

  const int lrow = lane & 15;
  const int lk = lane >> 4;
  const int sr = lane >> 3;                      // staging row within 8-row chunk
  const int pc = (((lane & 7) ^ sr) << 3);       // permuted global col (elements)
  const int r7 = lrow & 7;                       // reader row&7

  // stage one BK=64 K-tile into buffer `buf` (8 loads/thread: 4 A + 4 B)
  auto STAGE = [&](int kt, int buf) {
    unsigned short* As_ = smem + buf * BUF_SHORTS;
    unsigned short* Bs_ = As_ + MBLK * 64;
#pragma unroll
    for (int c = 0; c < MBLK / 32; ++c) {
      const int row = wave * (MBLK / 4) + c * 8;
      async_load16(Ab + kt + (unsigned long long)(row + sr) * lda + pc,
                   (void*)(As_ + row * 64));
    }
#pragma unroll
    for (int c = 0; c < 4; ++c) {
      const int row = wave * 32 + c * 8;
      async_load16(Bb + kt + (unsigned long long)(row + sr) * ldb + pc,
                   (void*)(Bs_ + row * 64));
    }
  };

  const int nt = K >> 6;
  STAGE(0, 0);
  STAGE(64, 1);
  for (int t = 0; t < nt; ++t) {
    if (t + 1 < nt) {
      asm volatile("s_waitcnt vmcnt(8)" ::: "memory");  // tile t landed; t+1 in flight
    } else {
      asm volatile("s_waitcnt vmcnt(0)" ::: "memory");
    }
    __builtin_amdgcn_s_barrier();  // all waves' tile-t loads landed
    const unsigned short* As = smem + (t & 1) * BUF_SHORTS;
    const unsigned short* Bs = As + MBLK * 64;
#pragma unroll
    for (int ks = 0; ks < 2; ++ks) {
      const int ko = (((ks << 2) + lk) ^ r7) << 3;
      short8 af[MI], bfr[4];
#pragma unroll
      for (int i = 0; i < MI; ++i)
        af[i] = *(const short8*)(As + (wm + i * 16 + lrow) * 64 + ko);
#pragma unroll
      for (int i = 0; i < 4; ++i)
        bfr[i] = *(const short8*)(Bs + (wn + i * 16 + lrow) * 64 + ko);
#pragma unroll
      for (int mi = 0; mi < MI; ++mi)
#pragma unroll
        for (int ni = 0; ni < 4; ++ni)
          acc[mi][ni] = __builtin_amdgcn_mfma_f32_16x16x32_bf16(af[mi], bfr[ni], acc[mi][ni], 0, 0, 0);
    }
    if (t + 2 < nt) {
      __builtin_amdgcn_s_barrier();  // all reads of buf[t&1] done (MFMAs issued)
      STAGE((t + 2) << 6, t & 1);    // restage freed buffer; in flight across next barrier
    }
  }

  const int r0 = lk * 4;  // C/D: row = (lane>>4)*4 + reg
  const int cn = lrow;    // C/D: col = lane&15

  if (MODE == 0) {
    const int which = n0 >> 9;  // 0=Q 1=K 2=V (128-tiles never straddle 512-boundaries)
#pragma unroll
    for (int ni = 0; ni < 4; ++ni) {
      const int o = n0 + wn + ni * 16 + cn;
      const float bi = bias[o];
      const int oin = o & 511;
      if (which < 2) {
        unsigned short* dst = (which == 0 ? out0 : out1) + (unsigned long long)b * 524288ull;
#pragma unroll
        for (int mi = 0; mi < MI; ++mi) {
          const int pbase = m0 + wm + mi * 16 + r0;
#pragma unroll
          for (int r = 0; r < 4; ++r)
            dst[(unsigned long long)(pbase + r) * 512ull + oin] = f2bf((acc[mi][ni][r] + bi) * scale);
        }
      } else {
        unsigned short* dst = out2 + (unsigned long long)b * 524288ull + (unsigned long long)oin * 1024ull;
#pragma unroll
        for (int mi = 0; mi < MI; ++mi) {
          const int pbase = m0 + wm + mi * 16 + r0;
          unsigned short h4[4] __attribute__((aligned(8)));
#pragma unroll
          for (int r = 0; r < 4; ++r) h4[r] = f2bf(acc[mi][ni][r] + bi);
          *(int2*)(dst + pbase) = *(int2*)h4;
        }
      }
    }
  } else if (MODE == 1) {
    // acc = S^T tile: j = m0+wm+mi*16+r0+r (row), i = n0+wn+ni*16+cn (col)
    // softmax over aligned 32-j groups (reference normalizes last spatial axis only)
#pragma unroll
    for (int mi = 0; mi < MI; ++mi)
#pragma unroll
      for (int ni = 0; ni < 4; ++ni)
#pragma unroll
        for (int r = 0; r < 4; ++r) acc[mi][ni][r] = __expf(acc[mi][ni][r]);
    float inv[4][MI / 2];
#pragma unroll
    for (int ni = 0; ni < 4; ++ni)
#pragma unroll
      for (int cp = 0; cp < MI / 2; ++cp) {
        float s8 = 0.f;
#pragma unroll
        for (int mm = 0; mm < 2; ++mm)
#pragma unroll
          for (int r = 0; r < 4; ++r) s8 += acc[cp * 2 + mm][ni][r];
        s8 += __shfl_xor(s8, 16);
        s8 += __shfl_xor(s8, 32);
        inv[ni][cp] = 1.f / s8;
      }
    // transpose P^T -> P[i][j] through LDS, two 64-i passes (Pt = 64x136 fits)
    unsigned short* Pt = smem;
    unsigned short* dst = out0 + (unsigned long long)b * 1048576ull;
#pragma unroll
    for (int half = 0; half < 2; ++half) {
      __syncthreads();
      if ((wn >> 6) == half) {
#pragma unroll
        for (int mi = 0; mi < MI; ++mi)
#pragma unroll
          for (int ni = 0; ni < 4; ++ni) {
            unsigned short p4[4] __attribute__((aligned(8)));
#pragma unroll
            for (int r = 0; r < 4; ++r) p4[r] = f2bf(acc[mi][ni][r] * inv[ni][mi >> 1]);
            const int li = ni * 16 + cn;          // 0..63 within this half
            const int lj = wm + mi * 16 + r0;
            *(int2*)(Pt + li * 136 + lj) = *(int2*)p4;
          }
      }
      __syncthreads();
#pragma unroll
      for (int it = 0; it < 4; ++it) {
        const int row = it * 16 + (tid >> 4);
        const int col = (tid & 15) * 8;
        int4 v = *(const int4*)(Pt + row * 136 + col);
        *(int4*)(dst + (unsigned long long)(n0 + half * 64 + row) * 1024ull + m0 + col) = v;
      }
    }
  } else if (MODE == 2) {
    unsigned short* dst = out0 + (unsigned long long)b * 524288ull;
#pragma unroll
    for (int mi = 0; mi < MI; ++mi) {
      const int ib = m0 + wm + mi * 16 + r0;
#pragma unroll
      for (int ni = 0; ni < 4; ++ni) {
        const int c = n0 + wn + ni * 16 + cn;
#pragma unroll
        for (int r = 0; r < 4; ++r)
          dst[(unsigned long long)(ib + r) * 512ull + c] = f2bf(acc[mi][ni][r]);
      }
    }
  } else {  // MODE 3: fp32 out = acc + bias + x, LDS-staged coalesced epilogue
    float* Pt = (float*)smem;                    // [128][66] f32 (33 KB, fits)
    float* dst = fout + (unsigned long long)b * 524288ull;
    const float* xr = xres + (unsigned long long)b * 524288ull;
#pragma unroll
    for (int half = 0; half < 2; ++half) {
      __syncthreads();
      if ((wn >> 6) == half) {                   // 2 waves own these 64 p-cols
#pragma unroll
        for (int mi = 0; mi < MI; ++mi)
#pragma unroll
          for (int ni = 0; ni < 4; ++ni) {
            const int col = ni * 16 + cn;        // 0..63 within half
#pragma unroll
            for (int r = 0; r < 4; ++r)
              Pt[(wm + mi * 16 + r0 + r) * 66 + col] = acc[mi][ni][r];
          }
      }
      __syncthreads();
      // 256 threads: 16 lanes x float4 cover 64 p-cols per row; 16 rows/pass
#pragma unroll
      for (int it = 0; it < 8; ++it) {
        const int row = it * 16 + (tid >> 4);    // o within tile
        const int col = (tid & 15) * 4;          // p offset within half
        const int o = m0 + row;
        const unsigned long long gidx = (unsigned long long)o * 1024ull + n0 + half * 64 + col;
        const float* ps = Pt + row * 66 + col;
        const float bi = bias[o];
        const float4 xv = *(const float4*)(xr + gidx);
        float4 ov;
        ov.x = ps[0] + bi + xv.x;
        ov.y = ps[1] + bi + xv.y;
        ov.z = ps[2] + bi + xv.z;
        ov.w = ps[3] + bi + xv.w;
        *(float4*)(dst + gidx) = ov;
      }
    }
  }
}

extern "C" void kernel_launch(void* const* d_in, const int* in_sizes, int n_in,
                              void* d_out, int out_size, void* d_ws, size_t ws_size,
                              hipStream_t stream) {
  const float* x     = (const float*)d_in[0];
  const float* gamma = (const float*)d_in[1];
  const float* beta  = (const float*)d_in[2];
  const float* qkvw  = (const float*)d_in[3];
  const float* qkvb  = (const float*)d_in[4];
  const float* projw = (const float*)d_in[5];
  const float* projb = (const float*)d_in[6];
  float* out = (float*)d_out;
  char* ws = (char*)d_ws;

  unsigned short* Hin = (unsigned short*)(ws);                        // 32 MB [b][p][c]
  unsigned short* Q   = (unsigned short*)(ws + 1ull * 33554432ull);   // 32 MB [b][p][c]
  unsigned short* Kb  = (unsigned short*)(ws + 2ull * 33554432ull);   // 32 MB [b][p][c]
  unsigned short* V   = (unsigned short*)(ws + 3ull * 33554432ull);   // 32 MB [b][c][p]
  unsigned short* S   = (unsigned short*)(ws + 4ull * 33554432ull);   // 64 MB P[b][i][j]
  unsigned short* Wq  = (unsigned short*)(ws + 6ull * 33554432ull);   // 1.5 MB
  unsigned short* Wp  = (unsigned short*)(ws + 6ull * 33554432ull + 2ull * 1048576ull);
  unsigned short* H   = Hin;  // reuse: Hin dead after QKV GEMM

  const float SCALE = 0.21022410381342864f;  // 512^-0.25
  dim3 blk(256);
  const float* nzf = nullptr;
  unsigned short* nzo = nullptr;
  float* nzfo = nullptr;

  hipLaunchKernelGGL(prep_k, dim3(2048), blk, 0, stream,
                     x, gamma, beta, Hin, qkvw, Wq, projw, Wp);
  hipLaunchKernelGGL((gemm_k<0, 4>), dim3(3072), blk, 0, stream,
                     Hin, 524288ull, 512, Wq, 0ull, 512, qkvb, nzf, Q, Kb, V, nzfo, SCALE, 512);
  // S^T: A = K (j rows), B = Q (i cols)
  hipLaunchKernelGGL((gemm_k<1, 4>), dim3(2048), blk, 0, stream,
                     Kb, 524288ull, 512, Q, 524288ull, 512, nzf, nzf, S, nzo, nzo, nzfo, 0.f, 512);
  hipLaunchKernelGGL((gemm_k<2, 4>), dim3(1024), blk, 0, stream,
                     S, 1048576ull, 1024, V, 524288ull, 1024, nzf, nzf, H, nzo, nzo, nzfo, 0.f, 1024);
  hipLaunchKernelGGL((gemm_k<3, 4>), dim3(8, 4, 32), blk, 0, stream,
                     Wp, 0ull, 512, H, 524288ull, 512, projb, x, nzo, nzo, nzo, out, 0.f, 512);
}

// Round 16
// 308.758 us; speedup vs baseline: 1.0492x; 1.0492x over previous
//
#include <hip/hip_runtime.h>

typedef __attribute__((ext_vector_type(8))) short short8;
typedef __attribute__((ext_vector_type(4))) float f32x4;

__device__ __forceinline__ float b2f(unsigned short u) {
  union { unsigned u32; float f; } x; x.u32 = ((unsigned)u) << 16; return x.f;
}
__device__ __forceinline__ unsigned short f2bf(float f) {
  union { float f; unsigned u; } x; x.f = f;
  unsigned r = x.u + 0x7fffu + ((x.u >> 16) & 1u);
  return (unsigned short)(r >> 16);
}
__device__ __forceinline__ void async_load16(const void* g, void* l) {
  __builtin_amdgcn_global_load_lds(
      (__attribute__((address_space(1))) void*)(void*)(g),
      (__attribute__((address_space(3))) void*)(l), 16, 0, 0);
}

// ---- merged: GroupNorm (blocks 0..1023) + weight fp32->bf16 cvt (blocks 1024..2047) ----
// Branch is blockIdx-uniform -> no divergent barrier. Saves one dispatch.
__global__ __launch_bounds__(256) void prep_k(
    const float* __restrict__ x, const float* __restrict__ gamma,
    const float* __restrict__ beta, unsigned short* __restrict__ hin,
    const float* __restrict__ wa, unsigned short* __restrict__ oa,
    const float* __restrict__ wb, unsigned short* __restrict__ ob) {
  if (blockIdx.x >= 1024) {
    int i = (blockIdx.x - 1024) * 256 + threadIdx.x;
    const float* src; unsigned short* dst; int idx;
    if (i < 196608) { src = wa; dst = oa; idx = i; }
    else if (i < 262144) { src = wb; dst = ob; idx = i - 196608; }
    else return;
    float4 v = ((const float4*)src)[idx];
    unsigned short o[4] __attribute__((aligned(8)));
    o[0] = f2bf(v.x); o[1] = f2bf(v.y); o[2] = f2bf(v.z); o[3] = f2bf(v.w);
    ((int2*)dst)[idx] = *(int2*)o;
    return;
  }
  const int b = blockIdx.x >> 5, g = blockIdx.x & 31;
  const float* xb = x + ((unsigned long long)b * 512ull + (unsigned long long)g * 16ull) * 1024ull;
  const int t = threadIdx.x;
  float4 xr[16];
  float s = 0.f, ss = 0.f;
#pragma unroll
  for (int c = 0; c < 16; ++c) {
    xr[c] = *(const float4*)(xb + c * 1024 + t * 4);
    s += xr[c].x + xr[c].y + xr[c].z + xr[c].w;
    ss += xr[c].x * xr[c].x + xr[c].y * xr[c].y + xr[c].z * xr[c].z + xr[c].w * xr[c].w;
  }
#pragma unroll
  for (int o = 32; o; o >>= 1) { s += __shfl_down(s, o); ss += __shfl_down(ss, o); }
  __shared__ float sred[8];
  if ((t & 63) == 0) { sred[t >> 6] = s; sred[4 + (t >> 6)] = ss; }
  __syncthreads();
  s = sred[0] + sred[1] + sred[2] + sred[3];
  ss = sred[4] + sred[5] + sred[6] + sred[7];
  const float mean = s * (1.f / 16384.f);
  const float rstd = rsqrtf(ss * (1.f / 16384.f) - mean * mean + 1e-5f);
  float ga[16], be[16];
#pragma unroll
  for (int c = 0; c < 16; ++c) {
    float gg = gamma[g * 16 + c] * rstd;
    ga[c] = gg;
    be[c] = beta[g * 16 + c] - mean * gg;
  }
#pragma unroll
  for (int p4 = 0; p4 < 4; ++p4) {
    unsigned short ov[16] __attribute__((aligned(16)));
#pragma unroll
    for (int c = 0; c < 16; ++c)
      ov[c] = f2bf(((const float*)&xr[c])[p4] * ga[c] + be[c]);
    unsigned short* dst = hin + ((unsigned long long)b * 1024ull + t * 4 + p4) * 512ull + g * 16;
    *(int4*)dst = *(int4*)ov;
    *(int4*)(dst + 8) = *(int4*)(ov + 8);
  }
}

// ---- GEMM: C[m][n] = sum_k A[m][k]*B[n][k], A/B bf16 K-contiguous, BK=64 ----
// 128x128 tile (MI=4), 256 threads / 4 waves (2Mx2N, per-wave 64x64), 32 KB LDS
// single-buffer — the m97-proven config, lb(256,4) exact register fit
// (VGPR 64 + AGPR 64 = 128/wave budget; r10 measured: VGPR 64, no spill).
// FINAL configuration after the full schedule x occupancy matrix was measured:
//   256-tile any schedule (1.6 blk/CU)            -> 84-100 us
//   128-tile single-buf lb3/lb4 (2.6 blk/CU)      -> 66 us   <- THIS
//   128-tile dbuf counted-vmcnt lb2 (1.5 blk/CU)  -> 73 us (occupancy loss wins)
//   128-tile lb5                                  -> spill, 149+ us
// Cross-block TLP at 2.6 blocks/CU is the latency-hiding mechanism; intra-block
// pipelining variants all lost more occupancy than they gained (r1-r4, r12).
// Staging rows are 128 B (64 ch); XOR swizzle chunk^(row&7) applied to GLOBAL
// source columns (LDS dest linear per global_load_lds rules); readers un-XOR.
// This exact pattern measured SQ_LDS_BANK_CONFLICT = 0.
// MODE 0: QKV (bias, scale q/k, V transposed [c][p]). XCD swizzle.
// MODE 1: S^T (A=K, B=Q) + segmented (32-j) softmax + 2-pass LDS transpose -> P[i][j].
// MODE 2: PV -> H[b][i][c] bf16.
// MODE 3: proj -> fout = x + bias + acc (fp32), LDS-staged coalesced epilogue.
template <int MODE, int MI>
__global__ __launch_bounds__(256, 4) void gemm_k(
    const unsigned short* __restrict__ A, unsigned long long sA, int lda,
    const unsigned short* __restrict__ B, unsigned long long sB, int ldb,
    const float* __restrict__ bias, const float* __restrict__ xres,
    unsigned short* __restrict__ out0, unsigned short* __restrict__ out1,
    unsigned short* __restrict__ out2, float* __restrict__ fout,
    float scale, int K) {
  constexpr int MBLK = MI * 32;  // 128
  constexpr int STAGE_SHORTS = MBLK * 64 + 128 * 64;            // 16384 = 32 KB
  constexpr int SMEM_SHORTS = (MODE == 3) ? (128 * 66 * 2) : STAGE_SHORTS;  // MODE3: 33 KB f32 pad
  __shared__ unsigned short smem[SMEM_SHORTS];
  unsigned short* As = smem;
  unsigned short* Bs = smem + MBLK * 64;
  const int tid = threadIdx.x;
  const int wave = tid >> 6, lane = tid & 63;

  int n_t, m_t, b;
  if (MODE == 0) {
    // 3072 blocks; 12 n-tiles of one (m,b) run consecutively per XCD -> A-tile L2 reuse
    const int L = blockIdx.x + gridDim.x * (blockIdx.y + gridDim.y * blockIdx.z);
    const int r8 = L & 7, q = L >> 3;
    n_t = q % 12;
    const int mb = (q / 12) * 8 + r8;
    m_t = mb & 7;
    b = mb >> 3;
  } else if (MODE == 1) {
    const int L = blockIdx.x + gridDim.x * (blockIdx.y + gridDim.y * blockIdx.z);
    const int slice = L & 7, t = L >> 3;
    b = slice * 4 + (t >> 6);
    const int rem = t & 63;
    m_t = rem >> 3;
    n_t = rem & 7;
  } else if (MODE == 2) {
    const int L = blockIdx.x + gridDim.x * (blockIdx.y + gridDim.y * blockIdx.z);
    const int slice = L & 7, t = L >> 3;
    b = slice * 4 + (t >> 5);
    const int rem = t & 31;
    m_t = rem >> 2;
    n_t = rem & 3;
  } else {
    n_t = blockIdx.x; m_t = blockIdx.y; b = blockIdx.z;
  }
  const int m0 = m_t * MBLK, n0 = n_t * 128;
  const int wm = (wave & 1) * (MI * 16), wn = (wave >> 1) * 64;
  const unsigned short* Ab = A + (unsigned long long)b * sA + (unsigned long long)m0 * lda;
  const unsigned short* Bb = B + (unsigned long long)b * sB + (unsigned long long)n0 * ldb;

  f32x4 acc[MI][4];
#pragma unroll
  for (int i = 0; i < MI; ++i)
#pragma unroll
    for (int j = 0; j < 4; ++j)
#pragma unroll
      for (int r = 0; r < 4; ++r) acc[i][j][r] = 0.f;

  const int lrow = lane & 15;
  const int lk = lane >> 4;
  const int sr = lane >> 3;                      // staging row within 8-row chunk
  const int pc = (((lane & 7) ^ sr) << 3);       // permuted global col (elements)
  const int r7 = lrow & 7;                       // reader row&7

  for (int kt = 0; kt < K; kt += 64) {
    {
#pragma unroll
      for (int c = 0; c < MBLK / 32; ++c) {
        const int row = wave * (MBLK / 4) + c * 8;
        async_load16(Ab + kt + (unsigned long long)(row + sr) * lda + pc,
                     (void*)(As + row * 64));
      }
#pragma unroll
      for (int c = 0; c < 4; ++c) {
        const int row = wave * 32 + c * 8;
        async_load16(Bb + kt + (unsigned long long)(row + sr) * ldb + pc,
                     (void*)(Bs + row * 64));
      }
    }
    __syncthreads();
#pragma unroll
    for (int ks = 0; ks < 2; ++ks) {
      const int ko = (((ks << 2) + lk) ^ r7) << 3;
      short8 af[MI], bfr[4];
#pragma unroll
      for (int i = 0; i < MI; ++i)
        af[i] = *(const short8*)(As + (wm + i * 16 + lrow) * 64 + ko);
#pragma unroll
      for (int i = 0; i < 4; ++i)
        bfr[i] = *(const short8*)(Bs + (wn + i * 16 + lrow) * 64 + ko);
#pragma unroll
      for (int mi = 0; mi < MI; ++mi)
#pragma unroll
        for (int ni = 0; ni < 4; ++ni)
          acc[mi][ni] = __builtin_amdgcn_mfma_f32_16x16x32_bf16(af[mi], bfr[ni], acc[mi][ni], 0, 0, 0);
    }
    __syncthreads();
  }

  const int r0 = lk * 4;  // C/D: row = (lane>>4)*4 + reg
  const int cn = lrow;    // C/D: col = lane&15

  if (MODE == 0) {
    const int which = n0 >> 9;  // 0=Q 1=K 2=V (128-tiles never straddle 512-boundaries)
#pragma unroll
    for (int ni = 0; ni < 4; ++ni) {
      const int o = n0 + wn + ni * 16 + cn;
      const float bi = bias[o];
      const int oin = o & 511;
      if (which < 2) {
        unsigned short* dst = (which == 0 ? out0 : out1) + (unsigned long long)b * 524288ull;
#pragma unroll
        for (int mi = 0; mi < MI; ++mi) {
          const int pbase = m0 + wm + mi * 16 + r0;
#pragma unroll
          for (int r = 0; r < 4; ++r)
            dst[(unsigned long long)(pbase + r) * 512ull + oin] = f2bf((acc[mi][ni][r] + bi) * scale);
        }
      } else {
        unsigned short* dst = out2 + (unsigned long long)b * 524288ull + (unsigned long long)oin * 1024ull;
#pragma unroll
        for (int mi = 0; mi < MI; ++mi) {
          const int pbase = m0 + wm + mi * 16 + r0;
          unsigned short h4[4] __attribute__((aligned(8)));
#pragma unroll
          for (int r = 0; r < 4; ++r) h4[r] = f2bf(acc[mi][ni][r] + bi);
          *(int2*)(dst + pbase) = *(int2*)h4;
        }
      }
    }
  } else if (MODE == 1) {
    // acc = S^T tile: j = m0+wm+mi*16+r0+r (row), i = n0+wn+ni*16+cn (col)
    // softmax over aligned 32-j groups (reference normalizes last spatial axis only)
#pragma unroll
    for (int mi = 0; mi < MI; ++mi)
#pragma unroll
      for (int ni = 0; ni < 4; ++ni)
#pragma unroll
        for (int r = 0; r < 4; ++r) acc[mi][ni][r] = __expf(acc[mi][ni][r]);
    float inv[4][MI / 2];
#pragma unroll
    for (int ni = 0; ni < 4; ++ni)
#pragma unroll
      for (int cp = 0; cp < MI / 2; ++cp) {
        float s8 = 0.f;
#pragma unroll
        for (int mm = 0; mm < 2; ++mm)
#pragma unroll
          for (int r = 0; r < 4; ++r) s8 += acc[cp * 2 + mm][ni][r];
        s8 += __shfl_xor(s8, 16);
        s8 += __shfl_xor(s8, 32);
        inv[ni][cp] = 1.f / s8;
      }
    // transpose P^T -> P[i][j] through LDS, two 64-i passes (Pt = 64x136 fits 32KB)
    unsigned short* Pt = smem;
    unsigned short* dst = out0 + (unsigned long long)b * 1048576ull;
#pragma unroll
    for (int half = 0; half < 2; ++half) {
      __syncthreads();
      if ((wn >> 6) == half) {
#pragma unroll
        for (int mi = 0; mi < MI; ++mi)
#pragma unroll
          for (int ni = 0; ni < 4; ++ni) {
            unsigned short p4[4] __attribute__((aligned(8)));
#pragma unroll
            for (int r = 0; r < 4; ++r) p4[r] = f2bf(acc[mi][ni][r] * inv[ni][mi >> 1]);
            const int li = ni * 16 + cn;          // 0..63 within this half
            const int lj = wm + mi * 16 + r0;
            *(int2*)(Pt + li * 136 + lj) = *(int2*)p4;
          }
      }
      __syncthreads();
#pragma unroll
      for (int it = 0; it < 4; ++it) {
        const int row = it * 16 + (tid >> 4);
        const int col = (tid & 15) * 8;
        int4 v = *(const int4*)(Pt + row * 136 + col);
        *(int4*)(dst + (unsigned long long)(n0 + half * 64 + row) * 1024ull + m0 + col) = v;
      }
    }
  } else if (MODE == 2) {
    unsigned short* dst = out0 + (unsigned long long)b * 524288ull;
#pragma unroll
    for (int mi = 0; mi < MI; ++mi) {
      const int ib = m0 + wm + mi * 16 + r0;
#pragma unroll
      for (int ni = 0; ni < 4; ++ni) {
        const int c = n0 + wn + ni * 16 + cn;
#pragma unroll
        for (int r = 0; r < 4; ++r)
          dst[(unsigned long long)(ib + r) * 512ull + c] = f2bf(acc[mi][ni][r]);
      }
    }
  } else {  // MODE 3: fp32 out = acc + bias + x, LDS-staged coalesced epilogue
    float* Pt = (float*)smem;                    // [128][66] f32
    float* dst = fout + (unsigned long long)b * 524288ull;
    const float* xr = xres + (unsigned long long)b * 524288ull;
#pragma unroll
    for (int half = 0; half < 2; ++half) {
      __syncthreads();
      if ((wn >> 6) == half) {                   // 2 waves own these 64 p-cols
#pragma unroll
        for (int mi = 0; mi < MI; ++mi)
#pragma unroll
          for (int ni = 0; ni < 4; ++ni) {
            const int col = ni * 16 + cn;        // 0..63 within half
#pragma unroll
            for (int r = 0; r < 4; ++r)
              Pt[(wm + mi * 16 + r0 + r) * 66 + col] = acc[mi][ni][r];
          }
      }
      __syncthreads();
      // 256 threads: 16 lanes x float4 cover 64 p-cols per row; 16 rows/pass
#pragma unroll
      for (int it = 0; it < 8; ++it) {
        const int row = it * 16 + (tid >> 4);    // o within tile
        const int col = (tid & 15) * 4;          // p offset within half
        const int o = m0 + row;
        const unsigned long long gidx = (unsigned long long)o * 1024ull + n0 + half * 64 + col;
        const float* ps = Pt + row * 66 + col;
        const float bi = bias[o];
        const float4 xv = *(const float4*)(xr + gidx);
        float4 ov;
        ov.x = ps[0] + bi + xv.x;
        ov.y = ps[1] + bi + xv.y;
        ov.z = ps[2] + bi + xv.z;
        ov.w = ps[3] + bi + xv.w;
        *(float4*)(dst + gidx) = ov;
      }
    }
  }
}

extern "C" void kernel_launch(void* const* d_in, const int* in_sizes, int n_in,
                              void* d_out, int out_size, void* d_ws, size_t ws_size,
                              hipStream_t stream) {
  const float* x     = (const float*)d_in[0];
  const float* gamma = (const float*)d_in[1];
  const float* beta  = (const float*)d_in[2];
  const float* qkvw  = (const float*)d_in[3];
  const float* qkvb  = (const float*)d_in[4];
  const float* projw = (const float*)d_in[5];
  const float* projb = (const float*)d_in[6];
  float* out = (float*)d_out;
  char* ws = (char*)d_ws;

  unsigned short* Hin = (unsigned short*)(ws);                        // 32 MB [b][p][c]
  unsigned short* Q   = (unsigned short*)(ws + 1ull * 33554432ull);   // 32 MB [b][p][c]
  unsigned short* Kb  = (unsigned short*)(ws + 2ull * 33554432ull);   // 32 MB [b][p][c]
  unsigned short* V   = (unsigned short*)(ws + 3ull * 33554432ull);   // 32 MB [b][c][p]
  unsigned short* S   = (unsigned short*)(ws + 4ull * 33554432ull);   // 64 MB P[b][i][j]
  unsigned short* Wq  = (unsigned short*)(ws + 6ull * 33554432ull);   // 1.5 MB
  unsigned short* Wp  = (unsigned short*)(ws + 6ull * 33554432ull + 2ull * 1048576ull);
  unsigned short* H   = Hin;  // reuse: Hin dead after QKV GEMM

  const float SCALE = 0.21022410381342864f;  // 512^-0.25
  dim3 blk(256);
  const float* nzf = nullptr;
  unsigned short* nzo = nullptr;
  float* nzfo = nullptr;

  hipLaunchKernelGGL(prep_k, dim3(2048), blk, 0, stream,
                     x, gamma, beta, Hin, qkvw, Wq, projw, Wp);
  hipLaunchKernelGGL((gemm_k<0, 4>), dim3(3072), blk, 0, stream,
                     Hin, 524288ull, 512, Wq, 0ull, 512, qkvb, nzf, Q, Kb, V, nzfo, SCALE, 512);
  // S^T: A = K (j rows), B = Q (i cols)
  hipLaunchKernelGGL((gemm_k<1, 4>), dim3(2048), blk, 0, stream,
                     Kb, 524288ull, 512, Q, 524288ull, 512, nzf, nzf, S, nzo, nzo, nzfo, 0.f, 512);
  hipLaunchKernelGGL((gemm_k<2, 4>), dim3(1024), blk, 0, stream,
                     S, 1048576ull, 1024, V, 524288ull, 1024, nzf, nzf, H, nzo, nzo, nzfo, 0.f, 1024);
  hipLaunchKernelGGL((gemm_k<3, 4>), dim3(8, 4, 32), blk, 0, stream,
                     Wp, 0ull, 512, H, 524288ull, 512, projb, x, nzo, nzo, nzo, out, 0.f, 512);
}